// Round 1
// 5153.790 us; speedup vs baseline: 2.0783x; 2.0783x over previous
//
#include <hip/hip_runtime.h>

typedef unsigned short ushort_t;
typedef __attribute__((ext_vector_type(8))) short short8;
typedef __attribute__((ext_vector_type(4))) float floatx4;

#define TT 128
#define UNITS 512
#define EMBED 64
#define PATHN 8192
#define DECE 2048
#define MROWS 8192

__device__ __forceinline__ float bf2f(ushort_t u) {
  union { unsigned int i; float f; } v;
  v.i = ((unsigned int)u) << 16;
  return v.f;
}
__device__ __forceinline__ ushort_t f2bf(float f) {
  union { float f; unsigned int i; } v;
  v.f = f;
  unsigned int x = v.i;
  x += 0x7fffu + ((x >> 16) & 1u);  // RNE
  return (ushort_t)(x >> 16);
}
__device__ __forceinline__ float loadF(const void* p, size_t i, bool f32) {
  return f32 ? ((const float*)p)[i] : bf2f(((const ushort_t*)p)[i]);
}
__device__ __forceinline__ int loadI(const void* p, size_t i, bool i64) {
  return i64 ? (int)((const long long*)p)[i] : ((const int*)p)[i];
}

// mode[0]=1 iff float tensors are fp32 (else bf16); mode[1]=1 iff ints are int64.
__global__ void detect_mode(const void* __restrict__ emb, const void* __restrict__ tgt,
                            int* __restrict__ mode) {
  __shared__ int crazy, nz;
  if (threadIdx.x == 0) { crazy = 0; nz = 0; }
  __syncthreads();
  int c = 0;
  for (int i = threadIdx.x; i < 2048; i += 256) {  // emb has >=3520 elems either way
    ushort_t u = ((const ushort_t*)emb)[i];
    int e = (u >> 7) & 0xff;
    if (e > 0x90) c++;  // |v|>~1e5: impossible for 0.02-scale bf16 weights
  }
  if (c) atomicAdd(&crazy, c);
  if (threadIdx.x < 32) {
    int v = ((const int*)tgt)[threadIdx.x * 2 + 1];  // odd halves of first 32 int64s
    if (v != 0) atomicAdd(&nz, 1);
  }
  __syncthreads();
  if (threadIdx.x == 0) {
    mode[0] = (crazy > 16) ? 1 : 0;
    mode[1] = (nz == 0) ? 1 : 0;
  }
}

__global__ void gather_enc(const int* __restrict__ mode, const void* __restrict__ inputs,
                           const void* __restrict__ emb, ushort_t* __restrict__ out) {
  const bool f32 = mode[0] != 0, i64 = mode[1] != 0;
  int tid = blockIdx.x * blockDim.x + threadIdx.x;  // 8192*8
  int m = tid >> 3, part = tid & 7;
  int b = m & 63, t = m >> 6;
  int ch = loadI(inputs, (size_t)b * TT + t, i64);
  size_t src = (size_t)ch * EMBED + part * 8;
  ushort_t tmp[8];
  if (f32) {
#pragma unroll
    for (int j = 0; j < 8; j++) tmp[j] = f2bf(((const float*)emb)[src + j]);
  } else {
    *(short8*)tmp = *(const short8*)((const ushort_t*)emb + src);
  }
  *(short8*)(out + (size_t)m * EMBED + part * 8) = *(short8*)tmp;
}

__global__ void gather_dec(const int* __restrict__ mode, const void* __restrict__ targets,
                           const void* __restrict__ emb, ushort_t* __restrict__ out) {
  const bool f32 = mode[0] != 0, i64 = mode[1] != 0;
  int tid = blockIdx.x * blockDim.x + threadIdx.x;  // 8192*256
  int m = tid >> 8, part = tid & 255;
  int b = m & 63, t = m >> 6;
  int p = loadI(targets, (size_t)b * TT + t, i64);
  size_t src = (size_t)p * DECE + part * 8;
  ushort_t tmp[8];
  if (f32) {
#pragma unroll
    for (int j = 0; j < 8; j++) tmp[j] = f2bf(((const float*)emb)[src + j]);
  } else {
    *(short8*)tmp = *(const short8*)((const ushort_t*)emb + src);
  }
  *(short8*)(out + (size_t)m * DECE + part * 8) = *(short8*)tmp;
}

// transpose harness [R,C] (element offset eo) -> internal bf16 [C,R]
__global__ void transpose_elems(const int* __restrict__ mode, const void* __restrict__ in,
                                size_t eo, ushort_t* __restrict__ out, int R, int C) {
  const bool f32 = mode[0] != 0;
  __shared__ ushort_t tl[32][33];
  int c0 = blockIdx.x * 32, r0 = blockIdx.y * 32;
  int x = threadIdx.x & 31, y4 = threadIdx.x >> 5;  // 256 threads
#pragma unroll
  for (int i = 0; i < 4; i++) {
    int y = y4 + i * 8;
    tl[y][x] = f2bf(loadF(in, eo + (size_t)(r0 + y) * C + (c0 + x), f32));
  }
  __syncthreads();
#pragma unroll
  for (int i = 0; i < 4; i++) {
    int y = y4 + i * 8;
    out[(size_t)(c0 + y) * R + (r0 + x)] = tl[x][y];
  }
}

// MFMA GEMM: C = act(A[M,K] @ Bt[N,K]^T + bias). A/Bt internal bf16.
// bias harness dtype. Output bf16 internal, or TSTORE -> d_out (harness dtype,
// rows m=t*64+b stored as out[b][t][n]).
template <int RELU, int BIAS, int TSTORE>
__global__ __launch_bounds__(256) void gemm_bt(const int* __restrict__ mode,
                                               const ushort_t* __restrict__ A,
                                               const ushort_t* __restrict__ Bt,
                                               const void* __restrict__ bias,
                                               void* __restrict__ Cp, int M, int N, int K) {
  const bool f32 = mode[0] != 0;
  __shared__ __align__(16) ushort_t As[128 * 40];
  __shared__ __align__(16) ushort_t Bs[128 * 40];
  const int tid = threadIdx.x;
  const int lane = tid & 63, wv = tid >> 6;
  const int quad = lane >> 4, l16 = lane & 15;
  const int wrow = (wv & 1) * 64, wcol = (wv >> 1) * 64;
  floatx4 acc[4][4] = {};
  const int srow = tid >> 1, scol = (tid & 1) * 16;
  const ushort_t* Ag = A + (size_t)(blockIdx.y * 128 + srow) * K + scol;
  const ushort_t* Bg = Bt + (size_t)(blockIdx.x * 128 + srow) * K + scol;
  ushort_t* AsW = &As[srow * 40 + scol];
  ushort_t* BsW = &Bs[srow * 40 + scol];
  for (int k0 = 0; k0 < K; k0 += 32) {
    short8 a0 = *(const short8*)(Ag + k0);
    short8 a1 = *(const short8*)(Ag + k0 + 8);
    short8 b0 = *(const short8*)(Bg + k0);
    short8 b1 = *(const short8*)(Bg + k0 + 8);
    __syncthreads();
    *(short8*)AsW = a0;
    *(short8*)(AsW + 8) = a1;
    *(short8*)BsW = b0;
    *(short8*)(BsW + 8) = b1;
    __syncthreads();
    short8 af[4], bfr[4];
#pragma unroll
    for (int i = 0; i < 4; i++) af[i] = *(const short8*)&As[(wrow + i * 16 + l16) * 40 + quad * 8];
#pragma unroll
    for (int j = 0; j < 4; j++) bfr[j] = *(const short8*)&Bs[(wcol + j * 16 + l16) * 40 + quad * 8];
#pragma unroll
    for (int i = 0; i < 4; i++)
#pragma unroll
      for (int j = 0; j < 4; j++)
        acc[i][j] = __builtin_amdgcn_mfma_f32_16x16x32_bf16(af[i], bfr[j], acc[i][j], 0, 0, 0);
  }
  const int mbase = blockIdx.y * 128 + wrow;
  const int nbase = blockIdx.x * 128 + wcol;
#pragma unroll
  for (int j = 0; j < 4; j++) {
    int col = nbase + j * 16 + l16;
    float bv = BIAS ? loadF(bias, col, f32) : 0.0f;
#pragma unroll
    for (int i = 0; i < 4; i++) {
#pragma unroll
      for (int r = 0; r < 4; r++) {
        int row = mbase + i * 16 + quad * 4 + r;  // D: col=lane&15, row=quad*4+reg (m89/m91)
        float v = acc[i][j][r] + bv;
        if (RELU) v = fmaxf(v, 0.0f);
        if (TSTORE) {
          size_t o = (size_t)(row & 63) * ((size_t)TT * PATHN) + (size_t)(row >> 6) * PATHN + col;
          if (f32) ((float*)Cp)[o] = v;
          else ((ushort_t*)Cp)[o] = f2bf(v);
        } else {
          ((ushort_t*)Cp)[(size_t)row * N + col] = f2bf(v);
        }
      }
    }
  }
}

__device__ __forceinline__ void wait_flag(int* f) {
  while (__hip_atomic_load(f, __ATOMIC_RELAXED, __HIP_MEMORY_SCOPE_AGENT) < 32) {
  }
}

// Persistent pipelined LSTM over timesteps [t0,t1). Grid = 96 blocks:
// l = bx>>5 (layer), cb = bx&31 (16-unit column slice). 256 threads = 4 waves,
// wave wv owns rows wv*16..+16. Weights for (l,cb) cached in LDS (once);
// c-state lives in registers; h exchanged via hbuf parity ping-pong in global
// memory with device-scope flag sync (32 producers per (T,l)).
// Dep edges into (T,l): (T-1,l), (T,l-1), and WAR edge (T-2,l+1); all strictly
// decrease 2T+l => acyclic. 96 blocks at 1/CU (130KB LDS) are all co-resident.
__global__ __launch_bounds__(256) void lstm_persist(
    const int* __restrict__ mode, int t0, int t1, const ushort_t* __restrict__ z1,
    const ushort_t* __restrict__ Wxt, const ushort_t* __restrict__ Wht,
    const void* __restrict__ bias, ushort_t* __restrict__ hbuf, float* __restrict__ cbuf,
    ushort_t* __restrict__ decouts, int* __restrict__ flags) {
  const bool f32 = mode[0] != 0;
  const int l = blockIdx.x >> 5;
  const int cb = blockIdx.x & 31;
  const int tid = threadIdx.x;
  const int lane = tid & 63, wv = tid >> 6;
  const int quad = lane >> 4, l16 = lane & 15;
  const int col = cb * 16 + l16;

  // K padded 512->520 elems: row stride 1040B -> start bank 4*(l16+quad)%32,
  // 8 lanes per 4-bank group = the b128 minimum (conflict-free).
  __shared__ __align__(16) ushort_t Wh_s[64 * 520];
  __shared__ __align__(16) ushort_t Wx_s[64 * 520];

  {
    const ushort_t* WhG = Wht + (size_t)l * 2048 * 512;
    const ushort_t* WxG = Wxt + (size_t)l * 2048 * 512;
    for (int i = tid; i < 64 * 64; i += 256) {
      int r = i >> 6, kc = (i & 63) << 3;
      int g = r >> 4, c = r & 15;
      size_t grow = (size_t)g * 512 + cb * 16 + c;
      *(short8*)&Wh_s[r * 520 + kc] = *(const short8*)&WhG[grow * 512 + kc];
      if (l > 0) *(short8*)&Wx_s[r * 520 + kc] = *(const short8*)&WxG[grow * 512 + kc];
    }
  }
  floatx4 creg;
#pragma unroll
  for (int r = 0; r < 4; r++)
    creg[r] = cbuf[((size_t)l * 64 + wv * 16 + quad * 4 + r) * 512 + col];
  const float bi = loadF(bias, l * 2048 + col, f32);
  const float bff = loadF(bias, l * 2048 + 512 + col, f32);
  const float bg = loadF(bias, l * 2048 + 1024 + col, f32);
  const float bo = loadF(bias, l * 2048 + 1536 + col, f32);
  __syncthreads();

  const int arow = wv * 16 + l16;
  const int koff = quad * 8;

  for (int T = t0; T < t1; ++T) {
    const int pw = T & 1, pr = pw ^ 1;
    if (tid == 0) {
      if (l > 0) wait_flag(&flags[T * 3 + (l - 1)]);           // h_{l-1}(T) ready
      if (T > 0) wait_flag(&flags[(T - 1) * 3 + l]);           // h_l(T-1) ready (peers)
      if (l < 2 && T >= 2) wait_flag(&flags[(T - 2) * 3 + (l + 1)]);  // WAR: l+1 done reading
      __threadfence();  // acquire: invalidate L1/L2 before reading fresh h
    }
    __syncthreads();

    floatx4 acc[4] = {};
    if (l > 0) {
      const ushort_t* hX =
          hbuf + ((size_t)pw * 3 + (l - 1)) * 64 * 512 + (size_t)arow * 512 + koff;
#pragma unroll 4
      for (int k0 = 0; k0 < 512; k0 += 32) {
        short8 a = *(const short8*)(hX + k0);
#pragma unroll
        for (int g = 0; g < 4; g++) {
          short8 b = *(const short8*)&Wx_s[(g * 16 + l16) * 520 + k0 + koff];
          acc[g] = __builtin_amdgcn_mfma_f32_16x16x32_bf16(a, b, acc[g], 0, 0, 0);
        }
      }
    }
    {
      const ushort_t* hL = hbuf + ((size_t)pr * 3 + l) * 64 * 512 + (size_t)arow * 512 + koff;
#pragma unroll 4
      for (int k0 = 0; k0 < 512; k0 += 32) {
        short8 a = *(const short8*)(hL + k0);
#pragma unroll
        for (int g = 0; g < 4; g++) {
          short8 b = *(const short8*)&Wh_s[(g * 16 + l16) * 520 + k0 + koff];
          acc[g] = __builtin_amdgcn_mfma_f32_16x16x32_bf16(a, b, acc[g], 0, 0, 0);
        }
      }
    }
    ushort_t* hO = hbuf + ((size_t)pw * 3 + l) * 64 * 512;
#pragma unroll
    for (int r = 0; r < 4; r++) {
      int row = wv * 16 + quad * 4 + r;
      float zi = acc[0][r] + bi;
      float zf = acc[1][r] + bff;
      float zg = acc[2][r] + bg;
      float zo = acc[3][r] + bo;
      if (l == 0) {
        const ushort_t* zr = z1 + ((size_t)(T - t0) * 64 + row) * 2048;
        zi += bf2f(zr[col]);
        zf += bf2f(zr[512 + col]);
        zg += bf2f(zr[1024 + col]);
        zo += bf2f(zr[1536 + col]);
      }
      zi = fminf(fmaxf(zi, -30.f), 30.f);  // NaN/overflow guard
      zf = fminf(fmaxf(zf, -30.f), 30.f);
      zg = fminf(fmaxf(zg, -30.f), 30.f);
      zo = fminf(fmaxf(zo, -30.f), 30.f);
      float iv = 1.0f / (1.0f + expf(-zi));
      float fv = 1.0f / (1.0f + expf(-zf));
      float gv = tanhf(zg);
      float ov = 1.0f / (1.0f + expf(-zo));
      float cn = fv * creg[r] + iv * gv;
      creg[r] = cn;
      float hv = ov * tanhf(cn);
      hO[(size_t)row * 512 + col] = f2bf(hv);
      if (decouts && l == 2) decouts[((size_t)(T - t0) * 64 + row) * 512 + col] = f2bf(hv);
    }
    __syncthreads();  // all waves' h stores drained (barrier waits vmcnt(0))
    if (tid == 0) {
      __threadfence();  // release: write back L2 so other XCDs see h
      __hip_atomic_fetch_add(&flags[T * 3 + l], 1, __ATOMIC_RELEASE, __HIP_MEMORY_SCOPE_AGENT);
    }
  }
#pragma unroll
  for (int r = 0; r < 4; r++)
    cbuf[((size_t)l * 64 + wv * 16 + quad * 4 + r) * 512 + col] = creg[r];
}

extern "C" void kernel_launch(void* const* d_in, const int* in_sizes, int n_in, void* d_out,
                              int out_size, void* d_ws, size_t ws_size, hipStream_t stream) {
  const void* inputs = d_in[0];
  const void* targets = d_in[1];
  const void* input_embed = d_in[2];
  const void* enc_Wd = d_in[3];
  const void* enc_bd = d_in[4];
  const void* enc_Wx = d_in[5];
  const void* enc_Wh = d_in[6];
  const void* enc_b = d_in[7];
  const void* dec_embed = d_in[8];
  const void* dec_Wd = d_in[9];
  const void* dec_bd = d_in[10];
  const void* dec_Wx = d_in[11];
  const void* dec_Wh = d_in[12];
  const void* dec_b = d_in[13];
  const void* out_W1 = d_in[14];
  const void* out_b1 = d_in[15];
  const void* out_W2 = d_in[16];
  const void* out_b2 = d_in[17];

  char* ws = (char*)d_ws;
  size_t off = 0;
  auto alloc = [&](size_t bytes) {
    void* p = ws + off;
    off += (bytes + 255) & ~(size_t)255;
    return p;
  };
  int* mode = (int*)alloc(256);
  int* flags = (int*)alloc((size_t)256 * 3 * 4);
  ushort_t* encWd_t = (ushort_t*)alloc((size_t)512 * 64 * 2);
  ushort_t* encWx_t = (ushort_t*)alloc((size_t)3 * 2048 * 512 * 2);
  ushort_t* encWh_t = (ushort_t*)alloc((size_t)3 * 2048 * 512 * 2);
  ushort_t* decWd_t = (ushort_t*)alloc((size_t)512 * 2048 * 2);
  ushort_t* decWx_t = (ushort_t*)alloc((size_t)3 * 2048 * 512 * 2);
  ushort_t* decWh_t = (ushort_t*)alloc((size_t)3 * 2048 * 512 * 2);
  ushort_t* outW1_t = (ushort_t*)alloc((size_t)2048 * 512 * 2);
  ushort_t* encx = (ushort_t*)alloc((size_t)MROWS * EMBED * 2);
  ushort_t* encin = (ushort_t*)alloc((size_t)MROWS * 512 * 2);
  ushort_t* dect = (ushort_t*)alloc((size_t)MROWS * 2048 * 2);  // reused as out_W2^T
  ushort_t* decin = (ushort_t*)alloc((size_t)MROWS * 512 * 2);
  ushort_t* zbuf = (ushort_t*)alloc((size_t)MROWS * 2048 * 2);  // layer0 pre-acts
  ushort_t* hbuf = (ushort_t*)alloc((size_t)2 * 3 * 64 * 512 * 2);
  float* cbuf = (float*)alloc((size_t)3 * 64 * 512 * 4);
  ushort_t* decouts = (ushort_t*)alloc((size_t)MROWS * 512 * 2);
  ushort_t* h1 = (ushort_t*)alloc((size_t)MROWS * 2048 * 2);
  ushort_t* W2t = dect;

  hipMemsetAsync(hbuf, 0, (size_t)2 * 3 * 64 * 512 * 2, stream);
  hipMemsetAsync(cbuf, 0, (size_t)3 * 64 * 512 * 4, stream);
  hipMemsetAsync(flags, 0, (size_t)256 * 3 * 4, stream);

  detect_mode<<<1, 256, 0, stream>>>(input_embed, targets, mode);

  gather_enc<<<256, 256, 0, stream>>>(mode, inputs, input_embed, encx);
  gather_dec<<<8192, 256, 0, stream>>>(mode, targets, dec_embed, dect);

  transpose_elems<<<dim3(16, 2), 256, 0, stream>>>(mode, enc_Wd, 0, encWd_t, 64, 512);
  for (int l = 0; l < 3; l++) {
    size_t eo = (size_t)l * 512 * 2048;  // element offset of layer l in [3,512,2048]
    size_t to = (size_t)l * 2048 * 512;
    transpose_elems<<<dim3(64, 16), 256, 0, stream>>>(mode, enc_Wx, eo, encWx_t + to, 512, 2048);
    transpose_elems<<<dim3(64, 16), 256, 0, stream>>>(mode, enc_Wh, eo, encWh_t + to, 512, 2048);
    transpose_elems<<<dim3(64, 16), 256, 0, stream>>>(mode, dec_Wx, eo, decWx_t + to, 512, 2048);
    transpose_elems<<<dim3(64, 16), 256, 0, stream>>>(mode, dec_Wh, eo, decWh_t + to, 512, 2048);
  }
  transpose_elems<<<dim3(16, 64), 256, 0, stream>>>(mode, dec_Wd, 0, decWd_t, 2048, 512);
  transpose_elems<<<dim3(64, 16), 256, 0, stream>>>(mode, out_W1, 0, outW1_t, 512, 2048);

  // enc dense -> encin; enc layer0 pre-acts -> zbuf; dec dense -> decin
  gemm_bt<1, 1, 0><<<dim3(4, 64), 256, 0, stream>>>(mode, encx, encWd_t, enc_bd, encin, MROWS, 512, 64);
  gemm_bt<0, 0, 0><<<dim3(16, 64), 256, 0, stream>>>(mode, encin, encWx_t, nullptr, zbuf, MROWS, 2048, 512);
  gemm_bt<1, 1, 0><<<dim3(4, 64), 256, 0, stream>>>(mode, dect, decWd_t, dec_bd, decin, MROWS, 512, 2048);
  transpose_elems<<<dim3(256, 64), 256, 0, stream>>>(mode, out_W2, 0, W2t, 2048, 8192);

  // Encoder recurrence: one persistent pipelined kernel (timesteps 0..127)
  lstm_persist<<<96, 256, 0, stream>>>(mode, 0, 128, zbuf, encWx_t, encWh_t, enc_b, hbuf, cbuf,
                                       nullptr, flags);
  // Decoder layer0 pre-acts (zbuf reuse), then decoder recurrence (128..255)
  gemm_bt<0, 0, 0><<<dim3(16, 64), 256, 0, stream>>>(mode, decin, decWx_t, nullptr, zbuf, MROWS, 2048, 512);
  lstm_persist<<<96, 256, 0, stream>>>(mode, 128, 256, zbuf, decWx_t, decWh_t, dec_b, hbuf, cbuf,
                                       decouts, flags);

  gemm_bt<1, 1, 0><<<dim3(16, 64), 256, 0, stream>>>(mode, decouts, outW1_t, out_b1, h1, MROWS, 2048, 512);
  gemm_bt<1, 1, 1><<<dim3(64, 64), 256, 0, stream>>>(mode, h1, W2t, out_b2, d_out, MROWS, PATHN, 2048);
}

// Round 2
// 4353.854 us; speedup vs baseline: 2.4601x; 1.1837x over previous
//
#include <hip/hip_runtime.h>

typedef unsigned short ushort_t;
typedef unsigned long long u64_t;
typedef __attribute__((ext_vector_type(8))) short short8;
typedef __attribute__((ext_vector_type(4))) float floatx4;

#define TT 128
#define UNITS 512
#define EMBED 64
#define PATHN 8192
#define DECE 2048
#define MROWS 8192

__device__ __forceinline__ float bf2f(ushort_t u) {
  union { unsigned int i; float f; } v;
  v.i = ((unsigned int)u) << 16;
  return v.f;
}
__device__ __forceinline__ ushort_t f2bf(float f) {
  union { float f; unsigned int i; } v;
  v.f = f;
  unsigned int x = v.i;
  x += 0x7fffu + ((x >> 16) & 1u);  // RNE
  return (ushort_t)(x >> 16);
}
__device__ __forceinline__ float loadF(const void* p, size_t i, bool f32) {
  return f32 ? ((const float*)p)[i] : bf2f(((const ushort_t*)p)[i]);
}
__device__ __forceinline__ int loadI(const void* p, size_t i, bool i64) {
  return i64 ? (int)((const long long*)p)[i] : ((const int*)p)[i];
}

// mode[0]=1 iff float tensors are fp32 (else bf16); mode[1]=1 iff ints are int64.
__global__ void detect_mode(const void* __restrict__ emb, const void* __restrict__ tgt,
                            int* __restrict__ mode) {
  __shared__ int crazy, nz;
  if (threadIdx.x == 0) { crazy = 0; nz = 0; }
  __syncthreads();
  int c = 0;
  for (int i = threadIdx.x; i < 2048; i += 256) {  // emb has >=3520 elems either way
    ushort_t u = ((const ushort_t*)emb)[i];
    int e = (u >> 7) & 0xff;
    if (e > 0x90) c++;  // |v|>~1e5: impossible for 0.02-scale bf16 weights
  }
  if (c) atomicAdd(&crazy, c);
  if (threadIdx.x < 32) {
    int v = ((const int*)tgt)[threadIdx.x * 2 + 1];  // odd halves of first 32 int64s
    if (v != 0) atomicAdd(&nz, 1);
  }
  __syncthreads();
  if (threadIdx.x == 0) {
    mode[0] = (crazy > 16) ? 1 : 0;
    mode[1] = (nz == 0) ? 1 : 0;
  }
}

__global__ void gather_enc(const int* __restrict__ mode, const void* __restrict__ inputs,
                           const void* __restrict__ emb, ushort_t* __restrict__ out) {
  const bool f32 = mode[0] != 0, i64 = mode[1] != 0;
  int tid = blockIdx.x * blockDim.x + threadIdx.x;  // 8192*8
  int m = tid >> 3, part = tid & 7;
  int b = m & 63, t = m >> 6;
  int ch = loadI(inputs, (size_t)b * TT + t, i64);
  size_t src = (size_t)ch * EMBED + part * 8;
  ushort_t tmp[8];
  if (f32) {
#pragma unroll
    for (int j = 0; j < 8; j++) tmp[j] = f2bf(((const float*)emb)[src + j]);
  } else {
    *(short8*)tmp = *(const short8*)((const ushort_t*)emb + src);
  }
  *(short8*)(out + (size_t)m * EMBED + part * 8) = *(short8*)tmp;
}

__global__ void gather_dec(const int* __restrict__ mode, const void* __restrict__ targets,
                           const void* __restrict__ emb, ushort_t* __restrict__ out) {
  const bool f32 = mode[0] != 0, i64 = mode[1] != 0;
  int tid = blockIdx.x * blockDim.x + threadIdx.x;  // 8192*256
  int m = tid >> 8, part = tid & 255;
  int b = m & 63, t = m >> 6;
  int p = loadI(targets, (size_t)b * TT + t, i64);
  size_t src = (size_t)p * DECE + part * 8;
  ushort_t tmp[8];
  if (f32) {
#pragma unroll
    for (int j = 0; j < 8; j++) tmp[j] = f2bf(((const float*)emb)[src + j]);
  } else {
    *(short8*)tmp = *(const short8*)((const ushort_t*)emb + src);
  }
  *(short8*)(out + (size_t)m * DECE + part * 8) = *(short8*)tmp;
}

// transpose harness [R,C] (element offset eo) -> internal bf16 [C,R]
__global__ void transpose_elems(const int* __restrict__ mode, const void* __restrict__ in,
                                size_t eo, ushort_t* __restrict__ out, int R, int C) {
  const bool f32 = mode[0] != 0;
  __shared__ ushort_t tl[32][33];
  int c0 = blockIdx.x * 32, r0 = blockIdx.y * 32;
  int x = threadIdx.x & 31, y4 = threadIdx.x >> 5;  // 256 threads
#pragma unroll
  for (int i = 0; i < 4; i++) {
    int y = y4 + i * 8;
    tl[y][x] = f2bf(loadF(in, eo + (size_t)(r0 + y) * C + (c0 + x), f32));
  }
  __syncthreads();
#pragma unroll
  for (int i = 0; i < 4; i++) {
    int y = y4 + i * 8;
    out[(size_t)(c0 + y) * R + (r0 + x)] = tl[x][y];
  }
}

// MFMA GEMM: C = act(A[M,K] @ Bt[N,K]^T + bias). A/Bt internal bf16.
// bias harness dtype. Output bf16 internal, or TSTORE -> d_out (harness dtype,
// rows m=t*64+b stored as out[b][t][n]).
template <int RELU, int BIAS, int TSTORE>
__global__ __launch_bounds__(256) void gemm_bt(const int* __restrict__ mode,
                                               const ushort_t* __restrict__ A,
                                               const ushort_t* __restrict__ Bt,
                                               const void* __restrict__ bias,
                                               void* __restrict__ Cp, int M, int N, int K) {
  const bool f32 = mode[0] != 0;
  __shared__ __align__(16) ushort_t As[128 * 40];
  __shared__ __align__(16) ushort_t Bs[128 * 40];
  const int tid = threadIdx.x;
  const int lane = tid & 63, wv = tid >> 6;
  const int quad = lane >> 4, l16 = lane & 15;
  const int wrow = (wv & 1) * 64, wcol = (wv >> 1) * 64;
  floatx4 acc[4][4] = {};
  const int srow = tid >> 1, scol = (tid & 1) * 16;
  const ushort_t* Ag = A + (size_t)(blockIdx.y * 128 + srow) * K + scol;
  const ushort_t* Bg = Bt + (size_t)(blockIdx.x * 128 + srow) * K + scol;
  ushort_t* AsW = &As[srow * 40 + scol];
  ushort_t* BsW = &Bs[srow * 40 + scol];
  for (int k0 = 0; k0 < K; k0 += 32) {
    short8 a0 = *(const short8*)(Ag + k0);
    short8 a1 = *(const short8*)(Ag + k0 + 8);
    short8 b0 = *(const short8*)(Bg + k0);
    short8 b1 = *(const short8*)(Bg + k0 + 8);
    __syncthreads();
    *(short8*)AsW = a0;
    *(short8*)(AsW + 8) = a1;
    *(short8*)BsW = b0;
    *(short8*)(BsW + 8) = b1;
    __syncthreads();
    short8 af[4], bfr[4];
#pragma unroll
    for (int i = 0; i < 4; i++) af[i] = *(const short8*)&As[(wrow + i * 16 + l16) * 40 + quad * 8];
#pragma unroll
    for (int j = 0; j < 4; j++) bfr[j] = *(const short8*)&Bs[(wcol + j * 16 + l16) * 40 + quad * 8];
#pragma unroll
    for (int i = 0; i < 4; i++)
#pragma unroll
      for (int j = 0; j < 4; j++)
        acc[i][j] = __builtin_amdgcn_mfma_f32_16x16x32_bf16(af[i], bfr[j], acc[i][j], 0, 0, 0);
  }
  const int mbase = blockIdx.y * 128 + wrow;
  const int nbase = blockIdx.x * 128 + wcol;
#pragma unroll
  for (int j = 0; j < 4; j++) {
    int col = nbase + j * 16 + l16;
    float bv = BIAS ? loadF(bias, col, f32) : 0.0f;
#pragma unroll
    for (int i = 0; i < 4; i++) {
#pragma unroll
      for (int r = 0; r < 4; r++) {
        int row = mbase + i * 16 + quad * 4 + r;  // D: col=lane&15, row=quad*4+reg (m89/m91)
        float v = acc[i][j][r] + bv;
        if (RELU) v = fmaxf(v, 0.0f);
        if (TSTORE) {
          size_t o = (size_t)(row & 63) * ((size_t)TT * PATHN) + (size_t)(row >> 6) * PATHN + col;
          if (f32) ((float*)Cp)[o] = v;
          else ((ushort_t*)Cp)[o] = f2bf(v);
        } else {
          ((ushort_t*)Cp)[(size_t)row * N + col] = f2bf(v);
        }
      }
    }
  }
}

// --- fence-free agent-scope coherence helpers (all data via LLC, sc1) ---
__device__ __forceinline__ void waitf(int* f) {
  // relaxed agent-scope atomic load -> global_load sc1 (reads LLC, no fence)
  while (__hip_atomic_load(f, __ATOMIC_RELAXED, __HIP_MEMORY_SCOPE_AGENT) < 32) {
  }
}
__device__ __forceinline__ short8 load_h16(const ushort_t* p) {
  // two 8B agent-scope relaxed atomic loads: bypass stale L1/L2, read LLC.
  union { u64_t q[2]; short8 v; } u;
  u.q[0] = __hip_atomic_load((const u64_t*)p, __ATOMIC_RELAXED, __HIP_MEMORY_SCOPE_AGENT);
  u.q[1] = __hip_atomic_load((const u64_t*)p + 1, __ATOMIC_RELAXED, __HIP_MEMORY_SCOPE_AGENT);
  return u.v;
}
__device__ __forceinline__ void store_h(ushort_t* p, ushort_t v) {
  // agent-scope relaxed atomic store -> global_store_short sc1 (write-through to LLC)
  __hip_atomic_store(p, v, __ATOMIC_RELAXED, __HIP_MEMORY_SCOPE_AGENT);
}

// Persistent pipelined LSTM over timesteps [t0,t1). Grid = 96 blocks:
// l = bx>>5 (layer), cb = bx&31 (16-unit column slice). 256 threads = 4 waves,
// wave wv owns rows wv*16..+16. Weights for (l,cb) cached in LDS (once);
// c-state lives in registers; h exchanged via hbuf parity ping-pong THROUGH THE
// LLC (sc1 atomics) with flag sync (32 producers per (T,l)). NO fences anywhere:
// ordering = vmcnt drain at __syncthreads before the relaxed flag fetch_add
// (stores ack'd at LLC), consumer reads LLC after flag-spin + barrier.
// Dep edges into (T,l): (T-1,l), (T,l-1), and WAR edge (T-2,l+1); all strictly
// decrease 2T+l => acyclic. 96 blocks at 1/CU (130KB LDS) are all co-resident.
__global__ __launch_bounds__(256) void lstm_persist(
    const int* __restrict__ mode, int t0, int t1, const ushort_t* __restrict__ z1,
    const ushort_t* __restrict__ Wxt, const ushort_t* __restrict__ Wht,
    const void* __restrict__ bias, ushort_t* __restrict__ hbuf, float* __restrict__ cbuf,
    ushort_t* __restrict__ decouts, int* __restrict__ flags) {
  const bool f32 = mode[0] != 0;
  const int l = blockIdx.x >> 5;
  const int cb = blockIdx.x & 31;
  const int tid = threadIdx.x;
  const int lane = tid & 63, wv = tid >> 6;
  const int quad = lane >> 4, l16 = lane & 15;
  const int col = cb * 16 + l16;

  // K padded 512->520 elems: row stride 1040B -> start bank rotates per row,
  // 8 lanes per 4-bank group = the b128 minimum (conflict-free).
  __shared__ __align__(16) ushort_t Wh_s[64 * 520];
  __shared__ __align__(16) ushort_t Wx_s[64 * 520];

  {
    const ushort_t* WhG = Wht + (size_t)l * 2048 * 512;
    const ushort_t* WxG = Wxt + (size_t)l * 2048 * 512;
    for (int i = tid; i < 64 * 64; i += 256) {
      int r = i >> 6, kc = (i & 63) << 3;
      int g = r >> 4, c = r & 15;
      size_t grow = (size_t)g * 512 + cb * 16 + c;
      *(short8*)&Wh_s[r * 520 + kc] = *(const short8*)&WhG[grow * 512 + kc];
      if (l > 0) *(short8*)&Wx_s[r * 520 + kc] = *(const short8*)&WxG[grow * 512 + kc];
    }
  }
  floatx4 creg;
#pragma unroll
  for (int r = 0; r < 4; r++)
    creg[r] = cbuf[((size_t)l * 64 + wv * 16 + quad * 4 + r) * 512 + col];
  const float bi = loadF(bias, l * 2048 + col, f32);
  const float bff = loadF(bias, l * 2048 + 512 + col, f32);
  const float bg = loadF(bias, l * 2048 + 1024 + col, f32);
  const float bo = loadF(bias, l * 2048 + 1536 + col, f32);
  __syncthreads();

  const int arow = wv * 16 + l16;
  const int koff = quad * 8;

  for (int T = t0; T < t1; ++T) {
    const int pw = T & 1, pr = pw ^ 1;
    // Wait 1: peers done with step T-1 (h_l(T-1) at LLC; also clears same-layer
    // WAR on parity pw). Fold in cross-layer WAR: (T-2,l+1) done reading h_l(T-2).
    if (tid == 0) {
      if (T > 0) waitf(&flags[(T - 1) * 3 + l]);
      if (l < 2 && T >= 2) waitf(&flags[(T - 2) * 3 + (l + 1)]);
    }
    __syncthreads();

    floatx4 acc[4] = {};
    // Wh @ h_l(T-1): ready as soon as peer flag seen -> runs while layer l-1
    // may still be finishing step T (hides half the compute on the l-chain).
    {
      const ushort_t* hL = hbuf + ((size_t)pr * 3 + l) * 64 * 512 + (size_t)arow * 512 + koff;
#pragma unroll
      for (int k0 = 0; k0 < 512; k0 += 32) {
        short8 a = load_h16(hL + k0);
#pragma unroll
        for (int g = 0; g < 4; g++) {
          short8 b = *(const short8*)&Wh_s[(g * 16 + l16) * 520 + k0 + koff];
          acc[g] = __builtin_amdgcn_mfma_f32_16x16x32_bf16(a, b, acc[g], 0, 0, 0);
        }
      }
    }
    if (l > 0) {
      // Wait 2: h_{l-1}(T) ready at LLC.
      if (tid == 0) waitf(&flags[T * 3 + (l - 1)]);
      __syncthreads();
      const ushort_t* hX = hbuf + ((size_t)pw * 3 + (l - 1)) * 64 * 512 + (size_t)arow * 512 + koff;
#pragma unroll
      for (int k0 = 0; k0 < 512; k0 += 32) {
        short8 a = load_h16(hX + k0);
#pragma unroll
        for (int g = 0; g < 4; g++) {
          short8 b = *(const short8*)&Wx_s[(g * 16 + l16) * 520 + k0 + koff];
          acc[g] = __builtin_amdgcn_mfma_f32_16x16x32_bf16(a, b, acc[g], 0, 0, 0);
        }
      }
    }
    ushort_t* hO = hbuf + ((size_t)pw * 3 + l) * 64 * 512;
#pragma unroll
    for (int r = 0; r < 4; r++) {
      int row = wv * 16 + quad * 4 + r;
      float zi = acc[0][r] + bi;
      float zf = acc[1][r] + bff;
      float zg = acc[2][r] + bg;
      float zo = acc[3][r] + bo;
      if (l == 0) {
        const ushort_t* zr = z1 + ((size_t)(T - t0) * 64 + row) * 2048;
        zi += bf2f(zr[col]);
        zf += bf2f(zr[512 + col]);
        zg += bf2f(zr[1024 + col]);
        zo += bf2f(zr[1536 + col]);
      }
      zi = fminf(fmaxf(zi, -30.f), 30.f);  // NaN/overflow guard
      zf = fminf(fmaxf(zf, -30.f), 30.f);
      zg = fminf(fmaxf(zg, -30.f), 30.f);
      zo = fminf(fmaxf(zo, -30.f), 30.f);
      float iv = 1.0f / (1.0f + expf(-zi));
      float fv = 1.0f / (1.0f + expf(-zf));
      float gv = tanhf(zg);
      float ov = 1.0f / (1.0f + expf(-zo));
      float cn = fv * creg[r] + iv * gv;
      creg[r] = cn;
      float hv = ov * tanhf(cn);
      store_h(&hO[(size_t)row * 512 + col], f2bf(hv));  // sc1 -> LLC
      if (decouts && l == 2) decouts[((size_t)(T - t0) * 64 + row) * 512 + col] = f2bf(hv);
    }
    // Barrier drains each wave's vmcnt to 0 => all h stores ack'd at LLC
    // before tid0 publishes the flag (relaxed, no wbl2).
    __syncthreads();
    if (tid == 0)
      __hip_atomic_fetch_add(&flags[T * 3 + l], 1, __ATOMIC_RELAXED, __HIP_MEMORY_SCOPE_AGENT);
  }
#pragma unroll
  for (int r = 0; r < 4; r++)
    cbuf[((size_t)l * 64 + wv * 16 + quad * 4 + r) * 512 + col] = creg[r];
}

extern "C" void kernel_launch(void* const* d_in, const int* in_sizes, int n_in, void* d_out,
                              int out_size, void* d_ws, size_t ws_size, hipStream_t stream) {
  const void* inputs = d_in[0];
  const void* targets = d_in[1];
  const void* input_embed = d_in[2];
  const void* enc_Wd = d_in[3];
  const void* enc_bd = d_in[4];
  const void* enc_Wx = d_in[5];
  const void* enc_Wh = d_in[6];
  const void* enc_b = d_in[7];
  const void* dec_embed = d_in[8];
  const void* dec_Wd = d_in[9];
  const void* dec_bd = d_in[10];
  const void* dec_Wx = d_in[11];
  const void* dec_Wh = d_in[12];
  const void* dec_b = d_in[13];
  const void* out_W1 = d_in[14];
  const void* out_b1 = d_in[15];
  const void* out_W2 = d_in[16];
  const void* out_b2 = d_in[17];

  char* ws = (char*)d_ws;
  size_t off = 0;
  auto alloc = [&](size_t bytes) {
    void* p = ws + off;
    off += (bytes + 255) & ~(size_t)255;
    return p;
  };
  int* mode = (int*)alloc(256);
  int* flags = (int*)alloc((size_t)256 * 3 * 4);
  ushort_t* encWd_t = (ushort_t*)alloc((size_t)512 * 64 * 2);
  ushort_t* encWx_t = (ushort_t*)alloc((size_t)3 * 2048 * 512 * 2);
  ushort_t* encWh_t = (ushort_t*)alloc((size_t)3 * 2048 * 512 * 2);
  ushort_t* decWd_t = (ushort_t*)alloc((size_t)512 * 2048 * 2);
  ushort_t* decWx_t = (ushort_t*)alloc((size_t)3 * 2048 * 512 * 2);
  ushort_t* decWh_t = (ushort_t*)alloc((size_t)3 * 2048 * 512 * 2);
  ushort_t* outW1_t = (ushort_t*)alloc((size_t)2048 * 512 * 2);
  ushort_t* encx = (ushort_t*)alloc((size_t)MROWS * EMBED * 2);
  ushort_t* encin = (ushort_t*)alloc((size_t)MROWS * 512 * 2);
  ushort_t* dect = (ushort_t*)alloc((size_t)MROWS * 2048 * 2);  // reused as out_W2^T
  ushort_t* decin = (ushort_t*)alloc((size_t)MROWS * 512 * 2);
  ushort_t* zbuf = (ushort_t*)alloc((size_t)MROWS * 2048 * 2);  // layer0 pre-acts
  ushort_t* hbuf = (ushort_t*)alloc((size_t)2 * 3 * 64 * 512 * 2);
  float* cbuf = (float*)alloc((size_t)3 * 64 * 512 * 4);
  ushort_t* decouts = (ushort_t*)alloc((size_t)MROWS * 512 * 2);
  ushort_t* h1 = (ushort_t*)alloc((size_t)MROWS * 2048 * 2);
  ushort_t* W2t = dect;

  hipMemsetAsync(hbuf, 0, (size_t)2 * 3 * 64 * 512 * 2, stream);
  hipMemsetAsync(cbuf, 0, (size_t)3 * 64 * 512 * 4, stream);
  hipMemsetAsync(flags, 0, (size_t)256 * 3 * 4, stream);

  detect_mode<<<1, 256, 0, stream>>>(input_embed, targets, mode);

  gather_enc<<<256, 256, 0, stream>>>(mode, inputs, input_embed, encx);
  gather_dec<<<8192, 256, 0, stream>>>(mode, targets, dec_embed, dect);

  transpose_elems<<<dim3(16, 2), 256, 0, stream>>>(mode, enc_Wd, 0, encWd_t, 64, 512);
  for (int l = 0; l < 3; l++) {
    size_t eo = (size_t)l * 512 * 2048;  // element offset of layer l in [3,512,2048]
    size_t to = (size_t)l * 2048 * 512;
    transpose_elems<<<dim3(64, 16), 256, 0, stream>>>(mode, enc_Wx, eo, encWx_t + to, 512, 2048);
    transpose_elems<<<dim3(64, 16), 256, 0, stream>>>(mode, enc_Wh, eo, encWh_t + to, 512, 2048);
    transpose_elems<<<dim3(64, 16), 256, 0, stream>>>(mode, dec_Wx, eo, decWx_t + to, 512, 2048);
    transpose_elems<<<dim3(64, 16), 256, 0, stream>>>(mode, dec_Wh, eo, decWh_t + to, 512, 2048);
  }
  transpose_elems<<<dim3(16, 64), 256, 0, stream>>>(mode, dec_Wd, 0, decWd_t, 2048, 512);
  transpose_elems<<<dim3(64, 16), 256, 0, stream>>>(mode, out_W1, 0, outW1_t, 512, 2048);

  // enc dense -> encin; enc layer0 pre-acts -> zbuf; dec dense -> decin
  gemm_bt<1, 1, 0><<<dim3(4, 64), 256, 0, stream>>>(mode, encx, encWd_t, enc_bd, encin, MROWS, 512, 64);
  gemm_bt<0, 0, 0><<<dim3(16, 64), 256, 0, stream>>>(mode, encin, encWx_t, nullptr, zbuf, MROWS, 2048, 512);
  gemm_bt<1, 1, 0><<<dim3(4, 64), 256, 0, stream>>>(mode, dect, decWd_t, dec_bd, decin, MROWS, 512, 2048);
  transpose_elems<<<dim3(256, 64), 256, 0, stream>>>(mode, out_W2, 0, W2t, 2048, 8192);

  // Encoder recurrence: one persistent pipelined kernel (timesteps 0..127)
  lstm_persist<<<96, 256, 0, stream>>>(mode, 0, 128, zbuf, encWx_t, encWh_t, enc_b, hbuf, cbuf,
                                       nullptr, flags);
  // Decoder layer0 pre-acts (zbuf reuse), then decoder recurrence (128..255)
  gemm_bt<0, 0, 0><<<dim3(16, 64), 256, 0, stream>>>(mode, decin, decWx_t, nullptr, zbuf, MROWS, 2048, 512);
  lstm_persist<<<96, 256, 0, stream>>>(mode, 128, 256, zbuf, decWx_t, decWh_t, dec_b, hbuf, cbuf,
                                       decouts, flags);

  gemm_bt<1, 1, 0><<<dim3(16, 64), 256, 0, stream>>>(mode, decouts, outW1_t, out_b1, h1, MROWS, 2048, 512);
  gemm_bt<1, 1, 1><<<dim3(64, 64), 256, 0, stream>>>(mode, h1, W2t, out_b2, d_out, MROWS, PATHN, 2048);
}

// Round 3
// 3924.819 us; speedup vs baseline: 2.7290x; 1.1093x over previous
//
#include <hip/hip_runtime.h>

typedef unsigned short ushort_t;
typedef unsigned long long u64_t;
typedef __attribute__((ext_vector_type(8))) short short8;
typedef __attribute__((ext_vector_type(4))) float floatx4;

#define TT 128
#define UNITS 512
#define EMBED 64
#define PATHN 8192
#define DECE 2048
#define MROWS 8192

__device__ __forceinline__ float bf2f(ushort_t u) {
  union { unsigned int i; float f; } v;
  v.i = ((unsigned int)u) << 16;
  return v.f;
}
__device__ __forceinline__ ushort_t f2bf(float f) {
  union { float f; unsigned int i; } v;
  v.f = f;
  unsigned int x = v.i;
  x += 0x7fffu + ((x >> 16) & 1u);  // RNE
  return (ushort_t)(x >> 16);
}
__device__ __forceinline__ float loadF(const void* p, size_t i, bool f32) {
  return f32 ? ((const float*)p)[i] : bf2f(((const ushort_t*)p)[i]);
}
__device__ __forceinline__ int loadI(const void* p, size_t i, bool i64) {
  return i64 ? (int)((const long long*)p)[i] : ((const int*)p)[i];
}

// mode[0]=1 iff float tensors are fp32 (else bf16); mode[1]=1 iff ints are int64.
__global__ void detect_mode(const void* __restrict__ emb, const void* __restrict__ tgt,
                            int* __restrict__ mode) {
  __shared__ int crazy, nz;
  if (threadIdx.x == 0) { crazy = 0; nz = 0; }
  __syncthreads();
  int c = 0;
  for (int i = threadIdx.x; i < 2048; i += 256) {  // emb has >=3520 elems either way
    ushort_t u = ((const ushort_t*)emb)[i];
    int e = (u >> 7) & 0xff;
    if (e > 0x90) c++;  // |v|>~1e5: impossible for 0.02-scale bf16 weights
  }
  if (c) atomicAdd(&crazy, c);
  if (threadIdx.x < 32) {
    int v = ((const int*)tgt)[threadIdx.x * 2 + 1];  // odd halves of first 32 int64s
    if (v != 0) atomicAdd(&nz, 1);
  }
  __syncthreads();
  if (threadIdx.x == 0) {
    mode[0] = (crazy > 16) ? 1 : 0;
    mode[1] = (nz == 0) ? 1 : 0;
  }
}

__global__ void gather_enc(const int* __restrict__ mode, const void* __restrict__ inputs,
                           const void* __restrict__ emb, ushort_t* __restrict__ out) {
  const bool f32 = mode[0] != 0, i64 = mode[1] != 0;
  int tid = blockIdx.x * blockDim.x + threadIdx.x;  // 8192*8
  int m = tid >> 3, part = tid & 7;
  int b = m & 63, t = m >> 6;
  int ch = loadI(inputs, (size_t)b * TT + t, i64);
  size_t src = (size_t)ch * EMBED + part * 8;
  ushort_t tmp[8];
  if (f32) {
#pragma unroll
    for (int j = 0; j < 8; j++) tmp[j] = f2bf(((const float*)emb)[src + j]);
  } else {
    *(short8*)tmp = *(const short8*)((const ushort_t*)emb + src);
  }
  *(short8*)(out + (size_t)m * EMBED + part * 8) = *(short8*)tmp;
}

__global__ void gather_dec(const int* __restrict__ mode, const void* __restrict__ targets,
                           const void* __restrict__ emb, ushort_t* __restrict__ out) {
  const bool f32 = mode[0] != 0, i64 = mode[1] != 0;
  int tid = blockIdx.x * blockDim.x + threadIdx.x;  // 8192*256
  int m = tid >> 8, part = tid & 255;
  int b = m & 63, t = m >> 6;
  int p = loadI(targets, (size_t)b * TT + t, i64);
  size_t src = (size_t)p * DECE + part * 8;
  ushort_t tmp[8];
  if (f32) {
#pragma unroll
    for (int j = 0; j < 8; j++) tmp[j] = f2bf(((const float*)emb)[src + j]);
  } else {
    *(short8*)tmp = *(const short8*)((const ushort_t*)emb + src);
  }
  *(short8*)(out + (size_t)m * DECE + part * 8) = *(short8*)tmp;
}

// transpose harness [R,C] (element offset eo) -> internal bf16 [C,R]
__global__ void transpose_elems(const int* __restrict__ mode, const void* __restrict__ in,
                                size_t eo, ushort_t* __restrict__ out, int R, int C) {
  const bool f32 = mode[0] != 0;
  __shared__ ushort_t tl[32][33];
  int c0 = blockIdx.x * 32, r0 = blockIdx.y * 32;
  int x = threadIdx.x & 31, y4 = threadIdx.x >> 5;  // 256 threads
#pragma unroll
  for (int i = 0; i < 4; i++) {
    int y = y4 + i * 8;
    tl[y][x] = f2bf(loadF(in, eo + (size_t)(r0 + y) * C + (c0 + x), f32));
  }
  __syncthreads();
#pragma unroll
  for (int i = 0; i < 4; i++) {
    int y = y4 + i * 8;
    out[(size_t)(c0 + y) * R + (r0 + x)] = tl[x][y];
  }
}

// MFMA GEMM: C = act(A[M,K] @ Bt[N,K]^T + bias). A/Bt internal bf16.
// bias harness dtype. Output bf16 internal, or TSTORE -> d_out (harness dtype,
// rows m=t*64+b stored as out[b][t][n]).
template <int RELU, int BIAS, int TSTORE>
__global__ __launch_bounds__(256) void gemm_bt(const int* __restrict__ mode,
                                               const ushort_t* __restrict__ A,
                                               const ushort_t* __restrict__ Bt,
                                               const void* __restrict__ bias,
                                               void* __restrict__ Cp, int M, int N, int K) {
  const bool f32 = mode[0] != 0;
  __shared__ __align__(16) ushort_t As[128 * 40];
  __shared__ __align__(16) ushort_t Bs[128 * 40];
  const int tid = threadIdx.x;
  const int lane = tid & 63, wv = tid >> 6;
  const int quad = lane >> 4, l16 = lane & 15;
  const int wrow = (wv & 1) * 64, wcol = (wv >> 1) * 64;
  floatx4 acc[4][4] = {};
  const int srow = tid >> 1, scol = (tid & 1) * 16;
  const ushort_t* Ag = A + (size_t)(blockIdx.y * 128 + srow) * K + scol;
  const ushort_t* Bg = Bt + (size_t)(blockIdx.x * 128 + srow) * K + scol;
  ushort_t* AsW = &As[srow * 40 + scol];
  ushort_t* BsW = &Bs[srow * 40 + scol];
  for (int k0 = 0; k0 < K; k0 += 32) {
    short8 a0 = *(const short8*)(Ag + k0);
    short8 a1 = *(const short8*)(Ag + k0 + 8);
    short8 b0 = *(const short8*)(Bg + k0);
    short8 b1 = *(const short8*)(Bg + k0 + 8);
    __syncthreads();
    *(short8*)AsW = a0;
    *(short8*)(AsW + 8) = a1;
    *(short8*)BsW = b0;
    *(short8*)(BsW + 8) = b1;
    __syncthreads();
    short8 af[4], bfr[4];
#pragma unroll
    for (int i = 0; i < 4; i++) af[i] = *(const short8*)&As[(wrow + i * 16 + l16) * 40 + quad * 8];
#pragma unroll
    for (int j = 0; j < 4; j++) bfr[j] = *(const short8*)&Bs[(wcol + j * 16 + l16) * 40 + quad * 8];
#pragma unroll
    for (int i = 0; i < 4; i++)
#pragma unroll
      for (int j = 0; j < 4; j++)
        acc[i][j] = __builtin_amdgcn_mfma_f32_16x16x32_bf16(af[i], bfr[j], acc[i][j], 0, 0, 0);
  }
  const int mbase = blockIdx.y * 128 + wrow;
  const int nbase = blockIdx.x * 128 + wcol;
#pragma unroll
  for (int j = 0; j < 4; j++) {
    int col = nbase + j * 16 + l16;
    float bv = BIAS ? loadF(bias, col, f32) : 0.0f;
#pragma unroll
    for (int i = 0; i < 4; i++) {
#pragma unroll
      for (int r = 0; r < 4; r++) {
        int row = mbase + i * 16 + quad * 4 + r;  // D: col=lane&15, row=quad*4+reg (m89/m91)
        float v = acc[i][j][r] + bv;
        if (RELU) v = fmaxf(v, 0.0f);
        if (TSTORE) {
          size_t o = (size_t)(row & 63) * ((size_t)TT * PATHN) + (size_t)(row >> 6) * PATHN + col;
          if (f32) ((float*)Cp)[o] = v;
          else ((ushort_t*)Cp)[o] = f2bf(v);
        } else {
          ((ushort_t*)Cp)[(size_t)row * N + col] = f2bf(v);
        }
      }
    }
  }
}

// --- fence-free agent-scope coherence helpers (all data via LLC, sc1) ---
__device__ __forceinline__ short8 load_h16(const ushort_t* p) {
  // two 8B agent-scope relaxed atomic loads: bypass stale L1/L2, read LLC.
  union { u64_t q[2]; short8 v; } u;
  u.q[0] = __hip_atomic_load((const u64_t*)p, __ATOMIC_RELAXED, __HIP_MEMORY_SCOPE_AGENT);
  u.q[1] = __hip_atomic_load((const u64_t*)p + 1, __ATOMIC_RELAXED, __HIP_MEMORY_SCOPE_AGENT);
  return u.v;
}
__device__ __forceinline__ void store_h(ushort_t* p, ushort_t v) {
  // agent-scope relaxed atomic store -> write-through to LLC
  __hip_atomic_store(p, v, __ATOMIC_RELAXED, __HIP_MEMORY_SCOPE_AGENT);
}
// Flag layout: per (T,l): 32 producer slots, each padded to 32 ints (128B line)
// -> no same-address/same-line contention between producers; store-only publish.
__device__ __forceinline__ int* fgrp(int* flags, int T, int l) {
  return flags + ((size_t)(T * 3 + l) << 10);  // 1024 ints per group
}
// Wave-0 parallel detect: lanes 0-31 poll g1's 32 slots, lanes 32-63 poll g2's.
__device__ __forceinline__ void wait_grp(const int* g1, const int* g2, int lane) {
  const int* p = ((lane < 32) ? g1 : g2) + (lane & 31) * 32;
  while (!__all(__hip_atomic_load(p, __ATOMIC_RELAXED, __HIP_MEMORY_SCOPE_AGENT) != 0)) {
  }
}

// Persistent pipelined LSTM over timesteps [t0,t1). Grid = 96 blocks:
// l = bx>>5 (layer), cb = bx&31 (16-unit column slice). 256 threads = 4 waves,
// wave wv owns rows wv*16..+16. Weights for (l,cb) cached in LDS (once);
// c-state lives in registers; h exchanged via hbuf 4-deep ring THROUGH THE LLC
// (sc1 atomics) with per-producer padded flags (store-only publish, parallel
// 32-lane detect). NO fences: ordering = vmcnt drain at __syncthreads before
// the relaxed flag store; consumer reads LLC after flag-spin + barrier.
// Deps into (T,l): (T-1,l) peers, (T,l-1) input, WAR (T-4,l+1) via 4-deep ring;
// all strictly backward in 2T+l => acyclic; 96 blocks at 1/CU co-resident.
__global__ __launch_bounds__(256) void lstm_persist(
    const int* __restrict__ mode, int t0, int t1, const ushort_t* __restrict__ z1,
    const ushort_t* __restrict__ Wxt, const ushort_t* __restrict__ Wht,
    const void* __restrict__ bias, ushort_t* __restrict__ hbuf, float* __restrict__ cbuf,
    ushort_t* __restrict__ decouts, int* __restrict__ flags) {
  const bool f32 = mode[0] != 0;
  const int l = blockIdx.x >> 5;
  const int cb = blockIdx.x & 31;
  const int tid = threadIdx.x;
  const int lane = tid & 63, wv = tid >> 6;
  const int quad = lane >> 4, l16 = lane & 15;
  const int col = cb * 16 + l16;

  // K padded 512->520 elems: row stride 1040B -> start bank rotates per row,
  // 8 lanes per 4-bank group = the b128 minimum (conflict-free).
  __shared__ __align__(16) ushort_t Wh_s[64 * 520];
  __shared__ __align__(16) ushort_t Wx_s[64 * 520];

  {
    const ushort_t* WhG = Wht + (size_t)l * 2048 * 512;
    const ushort_t* WxG = Wxt + (size_t)l * 2048 * 512;
    for (int i = tid; i < 64 * 64; i += 256) {
      int r = i >> 6, kc = (i & 63) << 3;
      int g = r >> 4, c = r & 15;
      size_t grow = (size_t)g * 512 + cb * 16 + c;
      *(short8*)&Wh_s[r * 520 + kc] = *(const short8*)&WhG[grow * 512 + kc];
      if (l > 0) *(short8*)&Wx_s[r * 520 + kc] = *(const short8*)&WxG[grow * 512 + kc];
    }
  }
  floatx4 creg;
#pragma unroll
  for (int r = 0; r < 4; r++)
    creg[r] = cbuf[((size_t)l * 64 + wv * 16 + quad * 4 + r) * 512 + col];
  const float bi = loadF(bias, l * 2048 + col, f32);
  const float bff = loadF(bias, l * 2048 + 512 + col, f32);
  const float bg = loadF(bias, l * 2048 + 1024 + col, f32);
  const float bo = loadF(bias, l * 2048 + 1536 + col, f32);
  __syncthreads();

  const int arow = wv * 16 + l16;
  const int koff = quad * 8;

  for (int T = t0; T < t1; ++T) {
    const int pw = T & 3, pr = (T - 1) & 3;  // 4-deep h ring
    if (T > 0) {
      if (wv == 0) {
        const int* g1 = fgrp(flags, T - 1, l);                                  // peers
        const int* g2 = (l < 2 && T >= 4) ? fgrp(flags, T - 4, l + 1) : g1;     // WAR
        wait_grp(g1, g2, lane);
      }
      __syncthreads();
    }

    floatx4 acc[4] = {};
    // Wh @ h_l(T-1): ready as soon as peer flags seen -> runs while layer l-1
    // may still be finishing step T (hides half the compute on the l-chain).
    {
      const ushort_t* hL = hbuf + ((size_t)pr * 3 + l) * 64 * 512 + (size_t)arow * 512 + koff;
#pragma unroll
      for (int k0 = 0; k0 < 512; k0 += 32) {
        short8 a = load_h16(hL + k0);
#pragma unroll
        for (int g = 0; g < 4; g++) {
          short8 b = *(const short8*)&Wh_s[(g * 16 + l16) * 520 + k0 + koff];
          acc[g] = __builtin_amdgcn_mfma_f32_16x16x32_bf16(a, b, acc[g], 0, 0, 0);
        }
      }
    }
    if (l > 0) {
      if (wv == 0) {
        const int* g = fgrp(flags, T, l - 1);  // h_{l-1}(T) ready at LLC
        wait_grp(g, g, lane);
      }
      __syncthreads();
      const ushort_t* hX = hbuf + ((size_t)pw * 3 + (l - 1)) * 64 * 512 + (size_t)arow * 512 + koff;
#pragma unroll
      for (int k0 = 0; k0 < 512; k0 += 32) {
        short8 a = load_h16(hX + k0);
#pragma unroll
        for (int g = 0; g < 4; g++) {
          short8 b = *(const short8*)&Wx_s[(g * 16 + l16) * 520 + k0 + koff];
          acc[g] = __builtin_amdgcn_mfma_f32_16x16x32_bf16(a, b, acc[g], 0, 0, 0);
        }
      }
    }
    ushort_t* hO = hbuf + ((size_t)pw * 3 + l) * 64 * 512;
#pragma unroll
    for (int r = 0; r < 4; r++) {
      int row = wv * 16 + quad * 4 + r;
      float zi = acc[0][r] + bi;
      float zf = acc[1][r] + bff;
      float zg = acc[2][r] + bg;
      float zo = acc[3][r] + bo;
      if (l == 0) {
        const ushort_t* zr = z1 + ((size_t)(T - t0) * 64 + row) * 2048;
        zi += bf2f(zr[col]);
        zf += bf2f(zr[512 + col]);
        zg += bf2f(zr[1024 + col]);
        zo += bf2f(zr[1536 + col]);
      }
      zi = fminf(fmaxf(zi, -30.f), 30.f);  // NaN/overflow guard
      zf = fminf(fmaxf(zf, -30.f), 30.f);
      zg = fminf(fmaxf(zg, -30.f), 30.f);
      zo = fminf(fmaxf(zo, -30.f), 30.f);
      float iv = 1.0f / (1.0f + expf(-zi));
      float fv = 1.0f / (1.0f + expf(-zf));
      float gv = tanhf(zg);
      float ov = 1.0f / (1.0f + expf(-zo));
      float cn = fv * creg[r] + iv * gv;
      creg[r] = cn;
      float hv = ov * tanhf(cn);
      store_h(&hO[(size_t)row * 512 + col], f2bf(hv));  // sc1 -> LLC
      if (decouts && l == 2) decouts[((size_t)(T - t0) * 64 + row) * 512 + col] = f2bf(hv);
    }
    // Barrier drains each wave's vmcnt to 0 => all h stores ack'd at LLC
    // before tid0 publishes this block's private flag slot (store, no RMW).
    __syncthreads();
    if (tid == 0)
      __hip_atomic_store(fgrp(flags, T, l) + cb * 32, 1, __ATOMIC_RELAXED,
                         __HIP_MEMORY_SCOPE_AGENT);
  }
#pragma unroll
  for (int r = 0; r < 4; r++)
    cbuf[((size_t)l * 64 + wv * 16 + quad * 4 + r) * 512 + col] = creg[r];
}

extern "C" void kernel_launch(void* const* d_in, const int* in_sizes, int n_in, void* d_out,
                              int out_size, void* d_ws, size_t ws_size, hipStream_t stream) {
  const void* inputs = d_in[0];
  const void* targets = d_in[1];
  const void* input_embed = d_in[2];
  const void* enc_Wd = d_in[3];
  const void* enc_bd = d_in[4];
  const void* enc_Wx = d_in[5];
  const void* enc_Wh = d_in[6];
  const void* enc_b = d_in[7];
  const void* dec_embed = d_in[8];
  const void* dec_Wd = d_in[9];
  const void* dec_bd = d_in[10];
  const void* dec_Wx = d_in[11];
  const void* dec_Wh = d_in[12];
  const void* dec_b = d_in[13];
  const void* out_W1 = d_in[14];
  const void* out_b1 = d_in[15];
  const void* out_W2 = d_in[16];
  const void* out_b2 = d_in[17];

  char* ws = (char*)d_ws;
  size_t off = 0;
  auto alloc = [&](size_t bytes) {
    void* p = ws + off;
    off += (bytes + 255) & ~(size_t)255;
    return p;
  };
  int* mode = (int*)alloc(256);
  int* flags = (int*)alloc((size_t)768 * 1024 * 4);  // (T,l) x 32 slots x 128B
  ushort_t* encWd_t = (ushort_t*)alloc((size_t)512 * 64 * 2);
  ushort_t* encWx_t = (ushort_t*)alloc((size_t)3 * 2048 * 512 * 2);
  ushort_t* encWh_t = (ushort_t*)alloc((size_t)3 * 2048 * 512 * 2);
  ushort_t* decWd_t = (ushort_t*)alloc((size_t)512 * 2048 * 2);
  ushort_t* decWx_t = (ushort_t*)alloc((size_t)3 * 2048 * 512 * 2);
  ushort_t* decWh_t = (ushort_t*)alloc((size_t)3 * 2048 * 512 * 2);
  ushort_t* outW1_t = (ushort_t*)alloc((size_t)2048 * 512 * 2);
  ushort_t* encx = (ushort_t*)alloc((size_t)MROWS * EMBED * 2);
  ushort_t* encin = (ushort_t*)alloc((size_t)MROWS * 512 * 2);
  ushort_t* dect = (ushort_t*)alloc((size_t)MROWS * 2048 * 2);  // reused as out_W2^T
  ushort_t* decin = (ushort_t*)alloc((size_t)MROWS * 512 * 2);
  ushort_t* zbuf = (ushort_t*)alloc((size_t)MROWS * 2048 * 2);  // layer0 pre-acts
  ushort_t* hbuf = (ushort_t*)alloc((size_t)4 * 3 * 64 * 512 * 2);  // 4-deep ring
  float* cbuf = (float*)alloc((size_t)3 * 64 * 512 * 4);
  ushort_t* decouts = (ushort_t*)alloc((size_t)MROWS * 512 * 2);
  ushort_t* h1 = (ushort_t*)alloc((size_t)MROWS * 2048 * 2);
  ushort_t* W2t = dect;

  hipMemsetAsync(hbuf, 0, (size_t)4 * 3 * 64 * 512 * 2, stream);
  hipMemsetAsync(cbuf, 0, (size_t)3 * 64 * 512 * 4, stream);
  hipMemsetAsync(flags, 0, (size_t)768 * 1024 * 4, stream);

  detect_mode<<<1, 256, 0, stream>>>(input_embed, targets, mode);

  gather_enc<<<256, 256, 0, stream>>>(mode, inputs, input_embed, encx);
  gather_dec<<<8192, 256, 0, stream>>>(mode, targets, dec_embed, dect);

  transpose_elems<<<dim3(16, 2), 256, 0, stream>>>(mode, enc_Wd, 0, encWd_t, 64, 512);
  for (int l = 0; l < 3; l++) {
    size_t eo = (size_t)l * 512 * 2048;  // element offset of layer l in [3,512,2048]
    size_t to = (size_t)l * 2048 * 512;
    transpose_elems<<<dim3(64, 16), 256, 0, stream>>>(mode, enc_Wx, eo, encWx_t + to, 512, 2048);
    transpose_elems<<<dim3(64, 16), 256, 0, stream>>>(mode, enc_Wh, eo, encWh_t + to, 512, 2048);
    transpose_elems<<<dim3(64, 16), 256, 0, stream>>>(mode, dec_Wx, eo, decWx_t + to, 512, 2048);
    transpose_elems<<<dim3(64, 16), 256, 0, stream>>>(mode, dec_Wh, eo, decWh_t + to, 512, 2048);
  }
  transpose_elems<<<dim3(16, 64), 256, 0, stream>>>(mode, dec_Wd, 0, decWd_t, 2048, 512);
  transpose_elems<<<dim3(64, 16), 256, 0, stream>>>(mode, out_W1, 0, outW1_t, 512, 2048);

  // enc dense -> encin; enc layer0 pre-acts -> zbuf; dec dense -> decin
  gemm_bt<1, 1, 0><<<dim3(4, 64), 256, 0, stream>>>(mode, encx, encWd_t, enc_bd, encin, MROWS, 512, 64);
  gemm_bt<0, 0, 0><<<dim3(16, 64), 256, 0, stream>>>(mode, encin, encWx_t, nullptr, zbuf, MROWS, 2048, 512);
  gemm_bt<1, 1, 0><<<dim3(4, 64), 256, 0, stream>>>(mode, dect, decWd_t, dec_bd, decin, MROWS, 512, 2048);
  transpose_elems<<<dim3(256, 64), 256, 0, stream>>>(mode, out_W2, 0, W2t, 2048, 8192);

  // Encoder recurrence: one persistent pipelined kernel (timesteps 0..127)
  lstm_persist<<<96, 256, 0, stream>>>(mode, 0, 128, zbuf, encWx_t, encWh_t, enc_b, hbuf, cbuf,
                                       nullptr, flags);
  // Decoder layer0 pre-acts (zbuf reuse), then decoder recurrence (128..255)
  gemm_bt<0, 0, 0><<<dim3(16, 64), 256, 0, stream>>>(mode, decin, decWx_t, nullptr, zbuf, MROWS, 2048, 512);
  lstm_persist<<<96, 256, 0, stream>>>(mode, 128, 256, zbuf, decWx_t, decWh_t, dec_b, hbuf, cbuf,
                                       decouts, flags);

  gemm_bt<1, 1, 0><<<dim3(16, 64), 256, 0, stream>>>(mode, decouts, outW1_t, out_b1, h1, MROWS, 2048, 512);
  gemm_bt<1, 1, 1><<<dim3(64, 64), 256, 0, stream>>>(mode, h1, W2t, out_b2, d_out, MROWS, PATHN, 2048);
}

// Round 5
// 3901.142 us; speedup vs baseline: 2.7456x; 1.0061x over previous
//
#include <hip/hip_runtime.h>

typedef unsigned short ushort_t;
typedef unsigned long long u64_t;
typedef __attribute__((ext_vector_type(8))) short short8;
typedef __attribute__((ext_vector_type(4))) short bfx4;
typedef __attribute__((ext_vector_type(4))) float floatx4;

#define TT 128
#define UNITS 512
#define EMBED 64
#define PATHN 8192
#define DECE 2048
#define MROWS 8192

__device__ __forceinline__ float bf2f(ushort_t u) {
  union { unsigned int i; float f; } v;
  v.i = ((unsigned int)u) << 16;
  return v.f;
}
__device__ __forceinline__ ushort_t f2bf(float f) {
  union { float f; unsigned int i; } v;
  v.f = f;
  unsigned int x = v.i;
  x += 0x7fffu + ((x >> 16) & 1u);  // RNE
  return (ushort_t)(x >> 16);
}
__device__ __forceinline__ float loadF(const void* p, size_t i, bool f32) {
  return f32 ? ((const float*)p)[i] : bf2f(((const ushort_t*)p)[i]);
}
__device__ __forceinline__ int loadI(const void* p, size_t i, bool i64) {
  return i64 ? (int)((const long long*)p)[i] : ((const int*)p)[i];
}

// mode[0]=1 iff float tensors are fp32 (else bf16); mode[1]=1 iff ints are int64.
__global__ void detect_mode(const void* __restrict__ emb, const void* __restrict__ tgt,
                            int* __restrict__ mode) {
  __shared__ int crazy, nz;
  if (threadIdx.x == 0) { crazy = 0; nz = 0; }
  __syncthreads();
  int c = 0;
  for (int i = threadIdx.x; i < 2048; i += 256) {  // emb has >=3520 elems either way
    ushort_t u = ((const ushort_t*)emb)[i];
    int e = (u >> 7) & 0xff;
    if (e > 0x90) c++;  // |v|>~1e5: impossible for 0.02-scale bf16 weights
  }
  if (c) atomicAdd(&crazy, c);
  if (threadIdx.x < 32) {
    int v = ((const int*)tgt)[threadIdx.x * 2 + 1];  // odd halves of first 32 int64s
    if (v != 0) atomicAdd(&nz, 1);
  }
  __syncthreads();
  if (threadIdx.x == 0) {
    mode[0] = (crazy > 16) ? 1 : 0;
    mode[1] = (nz == 0) ? 1 : 0;
  }
}

__global__ void gather_enc(const int* __restrict__ mode, const void* __restrict__ inputs,
                           const void* __restrict__ emb, ushort_t* __restrict__ out) {
  const bool f32 = mode[0] != 0, i64 = mode[1] != 0;
  int tid = blockIdx.x * blockDim.x + threadIdx.x;  // 8192*8
  int m = tid >> 3, part = tid & 7;
  int b = m & 63, t = m >> 6;
  int ch = loadI(inputs, (size_t)b * TT + t, i64);
  size_t src = (size_t)ch * EMBED + part * 8;
  ushort_t tmp[8];
  if (f32) {
#pragma unroll
    for (int j = 0; j < 8; j++) tmp[j] = f2bf(((const float*)emb)[src + j]);
  } else {
    *(short8*)tmp = *(const short8*)((const ushort_t*)emb + src);
  }
  *(short8*)(out + (size_t)m * EMBED + part * 8) = *(short8*)tmp;
}

__global__ void gather_dec(const int* __restrict__ mode, const void* __restrict__ targets,
                           const void* __restrict__ emb, ushort_t* __restrict__ out) {
  const bool f32 = mode[0] != 0, i64 = mode[1] != 0;
  int tid = blockIdx.x * blockDim.x + threadIdx.x;  // 8192*256
  int m = tid >> 8, part = tid & 255;
  int b = m & 63, t = m >> 6;
  int p = loadI(targets, (size_t)b * TT + t, i64);
  size_t src = (size_t)p * DECE + part * 8;
  ushort_t tmp[8];
  if (f32) {
#pragma unroll
    for (int j = 0; j < 8; j++) tmp[j] = f2bf(((const float*)emb)[src + j]);
  } else {
    *(short8*)tmp = *(const short8*)((const ushort_t*)emb + src);
  }
  *(short8*)(out + (size_t)m * DECE + part * 8) = *(short8*)tmp;
}

// transpose harness [R,C] (element offset eo) -> internal bf16 [C,R]
__global__ void transpose_elems(const int* __restrict__ mode, const void* __restrict__ in,
                                size_t eo, ushort_t* __restrict__ out, int R, int C) {
  const bool f32 = mode[0] != 0;
  __shared__ ushort_t tl[32][33];
  int c0 = blockIdx.x * 32, r0 = blockIdx.y * 32;
  int x = threadIdx.x & 31, y4 = threadIdx.x >> 5;  // 256 threads
#pragma unroll
  for (int i = 0; i < 4; i++) {
    int y = y4 + i * 8;
    tl[y][x] = f2bf(loadF(in, eo + (size_t)(r0 + y) * C + (c0 + x), f32));
  }
  __syncthreads();
#pragma unroll
  for (int i = 0; i < 4; i++) {
    int y = y4 + i * 8;
    out[(size_t)(c0 + y) * R + (r0 + x)] = tl[x][y];
  }
}

// MFMA GEMM: C = act(A[M,K] @ Bt[N,K]^T + bias). A/Bt internal bf16.
// bias harness dtype. Output bf16 internal, or TSTORE -> d_out (harness dtype,
// rows m=t*64+b stored as out[b][t][n]).
template <int RELU, int BIAS, int TSTORE>
__global__ __launch_bounds__(256) void gemm_bt(const int* __restrict__ mode,
                                               const ushort_t* __restrict__ A,
                                               const ushort_t* __restrict__ Bt,
                                               const void* __restrict__ bias,
                                               void* __restrict__ Cp, int M, int N, int K) {
  const bool f32 = mode[0] != 0;
  __shared__ __align__(16) ushort_t As[128 * 40];
  __shared__ __align__(16) ushort_t Bs[128 * 40];
  const int tid = threadIdx.x;
  const int lane = tid & 63, wv = tid >> 6;
  const int quad = lane >> 4, l16 = lane & 15;
  const int wrow = (wv & 1) * 64, wcol = (wv >> 1) * 64;
  floatx4 acc[4][4] = {};
  const int srow = tid >> 1, scol = (tid & 1) * 16;
  const ushort_t* Ag = A + (size_t)(blockIdx.y * 128 + srow) * K + scol;
  const ushort_t* Bg = Bt + (size_t)(blockIdx.x * 128 + srow) * K + scol;
  ushort_t* AsW = &As[srow * 40 + scol];
  ushort_t* BsW = &Bs[srow * 40 + scol];
  for (int k0 = 0; k0 < K; k0 += 32) {
    short8 a0 = *(const short8*)(Ag + k0);
    short8 a1 = *(const short8*)(Ag + k0 + 8);
    short8 b0 = *(const short8*)(Bg + k0);
    short8 b1 = *(const short8*)(Bg + k0 + 8);
    __syncthreads();
    *(short8*)AsW = a0;
    *(short8*)(AsW + 8) = a1;
    *(short8*)BsW = b0;
    *(short8*)(BsW + 8) = b1;
    __syncthreads();
    short8 af[4], bfr[4];
#pragma unroll
    for (int i = 0; i < 4; i++) af[i] = *(const short8*)&As[(wrow + i * 16 + l16) * 40 + quad * 8];
#pragma unroll
    for (int j = 0; j < 4; j++) bfr[j] = *(const short8*)&Bs[(wcol + j * 16 + l16) * 40 + quad * 8];
#pragma unroll
    for (int i = 0; i < 4; i++)
#pragma unroll
      for (int j = 0; j < 4; j++)
        acc[i][j] = __builtin_amdgcn_mfma_f32_16x16x32_bf16(af[i], bfr[j], acc[i][j], 0, 0, 0);
  }
  const int mbase = blockIdx.y * 128 + wrow;
  const int nbase = blockIdx.x * 128 + wcol;
#pragma unroll
  for (int j = 0; j < 4; j++) {
    int col = nbase + j * 16 + l16;
    float bv = BIAS ? loadF(bias, col, f32) : 0.0f;
#pragma unroll
    for (int i = 0; i < 4; i++) {
#pragma unroll
      for (int r = 0; r < 4; r++) {
        int row = mbase + i * 16 + quad * 4 + r;  // D: col=lane&15, row=quad*4+reg (m89/m91)
        float v = acc[i][j][r] + bv;
        if (RELU) v = fmaxf(v, 0.0f);
        if (TSTORE) {
          size_t o = (size_t)(row & 63) * ((size_t)TT * PATHN) + (size_t)(row >> 6) * PATHN + col;
          if (f32) ((float*)Cp)[o] = v;
          else ((ushort_t*)Cp)[o] = f2bf(v);
        } else {
          ((ushort_t*)Cp)[(size_t)row * N + col] = f2bf(v);
        }
      }
    }
  }
}

// --- fence-free agent-scope coherence helpers (all cross-block data via LLC) ---
__device__ __forceinline__ short8 load_h16(const ushort_t* p) {
  union { u64_t q[2]; short8 v; } u;
  u.q[0] = __hip_atomic_load((const u64_t*)p, __ATOMIC_RELAXED, __HIP_MEMORY_SCOPE_AGENT);
  u.q[1] = __hip_atomic_load((const u64_t*)p + 1, __ATOMIC_RELAXED, __HIP_MEMORY_SCOPE_AGENT);
  return u.v;
}
// Flag layout: per (T,l): 32 producer slots, each padded to 32 ints (128B line).
__device__ __forceinline__ int* fgrp(int* flags, int T, int l) {
  return flags + ((size_t)(T * 3 + l) << 10);  // 1024 ints per group
}
// Wave-0 parallel detect: lanes 0-31 poll g1's 32 slots, lanes 32-63 poll g2's.
// Guarded spin: converts any (unexpected) protocol deadlock into a bounded-time
// wrong answer (absmax fail) instead of a container-killing hang. The guard adds
// one VALU op per poll RTT -- invisible on the hot path, never fires if correct.
__device__ __forceinline__ void wait_grp(const int* g1, const int* g2, int lane) {
  const int* p = ((lane < 32) ? g1 : g2) + (lane & 31) * 32;
  int guard = 0;
  while (!__all(__hip_atomic_load(p, __ATOMIC_RELAXED, __HIP_MEMORY_SCOPE_AGENT) != 0)) {
    if (++guard > 10000000) break;
  }
}

#define LOADW(WHG, WXG, BIASP)                                                              \
  {                                                                                         \
    const ushort_t* _wh = (WHG) + (size_t)l * 2048 * 512;                                   \
    const ushort_t* _wx = (WXG) + (size_t)l * 2048 * 512;                                   \
    _Pragma("unroll") for (int g = 0; g < 4; g++) {                                         \
      _Pragma("unroll") for (int kb = 0; kb < 4; kb++) {                                    \
        size_t rr = (size_t)(g * 512 + cb * 16 + l16) * 512 + kbase + kb * 32 + quad * 8;   \
        whf[g][kb] = *(const short8*)&_wh[rr];                                              \
        if (l > 0) wxf[g][kb] = *(const short8*)&_wx[rr];                                   \
      }                                                                                     \
    }                                                                                       \
    _Pragma("unroll") for (int g = 0; g < 4; g++) {                                         \
      _Pragma("unroll") for (int j = 0; j < 4; j++)                                         \
        bs[g][j] = loadF((BIASP), l * 2048 + g * 512 + col0 + j, f32);                      \
    }                                                                                       \
  }

// Merged persistent pipelined LSTM, timesteps 0..255 (enc 0..127, dec 128..255).
// Grid = 96 blocks: l = bx>>5 (layer), cb = bx&31 (16-unit column slice).
// 4 waves; wave wv owns K-chunk [wv*128, wv*128+128) with its Wh/Wx fragments
// in REGISTERS (128 VGPRs) -- no per-step LDS weight streaming. Per step each
// wave computes partial z (64 rows x 64 gate-cols) over its K-chunk; partials
// reduced via 70KB LDS; epilogue threads own (row, 4 cols) -> 8B sc1 h-store.
// c-state in registers for all 256 steps. h exchanged via 4-deep LLC ring with
// per-producer padded flags (store-only publish, 32-lane parallel detect).
// Deps into (T,l): (T-1,l) peers, (T,l-1) input, WAR (T-4,l+1); all strictly
// backward in 2T+l => acyclic; 96 blocks co-resident (96 < 256 CUs at any occ).
__global__ __launch_bounds__(256, 1) void lstm_persist(
    const int* __restrict__ mode, const ushort_t* __restrict__ z1e,
    const ushort_t* __restrict__ z1d, const ushort_t* __restrict__ WxtE,
    const ushort_t* __restrict__ WhtE, const void* __restrict__ biasE,
    const ushort_t* __restrict__ WxtD, const ushort_t* __restrict__ WhtD,
    const void* __restrict__ biasD, ushort_t* __restrict__ hbuf,
    ushort_t* __restrict__ decouts, int* __restrict__ flags) {
  const bool f32 = mode[0] != 0;
  const int l = blockIdx.x >> 5;
  const int cb = blockIdx.x & 31;
  const int tid = threadIdx.x;
  const int lane = tid & 63, wv = tid >> 6;
  const int quad = lane >> 4, l16 = lane & 15;
  const int kbase = wv * 128;
  const int erow = tid >> 2;          // epilogue row 0..63
  const int ec = (tid & 3) * 4;       // epilogue col offset in block slice
  const int col0 = cb * 16 + ec;

  __shared__ __align__(16) float zred[4][64][68];  // [wave][row][gate-col], padded

  short8 whf[4][4], wxf[4][4];  // [gate][kb] weight fragments in registers
  floatx4 bs[4];                // per-thread bias (4 gates x 4 cols)
  LOADW(WhtE, WxtE, biasE);

  floatx4 cstate = {};  // c for (erow, cols col0..col0+3), all 256 steps

  for (int T = 0; T < 256; ++T) {
    if (T > 0) {
      if (wv == 0) {
        const int* g1 = fgrp(flags, T - 1, l);                               // peers
        const int* g2 = (l < 2 && T >= 4) ? fgrp(flags, T - 4, l + 1) : g1;  // WAR
        wait_grp(g1, g2, lane);
      }
      __syncthreads();
    }
    if (T == TT) LOADW(WhtD, WxtD, biasD);  // switch to decoder weights

    floatx4 acc[4][4] = {};  // [row-tile][gate]
    const ushort_t* hL = hbuf + ((size_t)((T - 1) & 3) * 3 + l) * 64 * 512;
    short8 af[4][4];
#pragma unroll
    for (int i = 0; i < 4; i++)
#pragma unroll
      for (int kb = 0; kb < 4; kb++)
        af[i][kb] = load_h16(hL + (size_t)(i * 16 + l16) * 512 + kbase + kb * 32 + quad * 8);
    // overlap the l-1 detect with the Wh A-load round trip
    if (l > 0 && wv == 0) {
      const int* g = fgrp(flags, T, l - 1);
      wait_grp(g, g, lane);
    }
#pragma unroll
    for (int kb = 0; kb < 4; kb++)
#pragma unroll
      for (int i = 0; i < 4; i++)
#pragma unroll
        for (int g = 0; g < 4; g++)
          acc[i][g] =
              __builtin_amdgcn_mfma_f32_16x16x32_bf16(af[i][kb], whf[g][kb], acc[i][g], 0, 0, 0);
    if (l > 0) {
      __syncthreads();  // wv0 saw (T,l-1) flags
      const ushort_t* hX = hbuf + ((size_t)(T & 3) * 3 + (l - 1)) * 64 * 512;
#pragma unroll
      for (int i = 0; i < 4; i++)
#pragma unroll
        for (int kb = 0; kb < 4; kb++)
          af[i][kb] = load_h16(hX + (size_t)(i * 16 + l16) * 512 + kbase + kb * 32 + quad * 8);
#pragma unroll
      for (int kb = 0; kb < 4; kb++)
#pragma unroll
        for (int i = 0; i < 4; i++)
#pragma unroll
          for (int g = 0; g < 4; g++)
            acc[i][g] =
                __builtin_amdgcn_mfma_f32_16x16x32_bf16(af[i][kb], wxf[g][kb], acc[i][g], 0, 0, 0);
    }
    // K-partials -> LDS (D: col=l16, row=quad*4+r)
#pragma unroll
    for (int i = 0; i < 4; i++)
#pragma unroll
      for (int g = 0; g < 4; g++)
#pragma unroll
        for (int r = 0; r < 4; r++)
          zred[wv][i * 16 + quad * 4 + r][g * 16 + l16] = acc[i][g][r];
    __syncthreads();

    // epilogue: thread owns (erow, 4 cols)
    ushort_t* hO = hbuf + ((size_t)(T & 3) * 3 + l) * 64 * 512;
    floatx4 z[4];
#pragma unroll
    for (int g = 0; g < 4; g++) {
      floatx4 s = *(const floatx4*)&zred[0][erow][g * 16 + ec];
#pragma unroll
      for (int w = 1; w < 4; w++) s += *(const floatx4*)&zred[w][erow][g * 16 + ec];
      z[g] = s + bs[g];
    }
    if (l == 0) {
      const ushort_t* zr = ((T < TT) ? z1e + ((size_t)T * 64 + erow) * 2048
                                     : z1d + ((size_t)(T - TT) * 64 + erow) * 2048) +
                           cb * 16 + ec;
#pragma unroll
      for (int g = 0; g < 4; g++) {
        bfx4 v = *(const bfx4*)(zr + g * 512);
#pragma unroll
        for (int j = 0; j < 4; j++) z[g][j] += bf2f((ushort_t)v[j]);
      }
    }
    union { ushort_t s[4]; u64_t q; } up;
#pragma unroll
    for (int j = 0; j < 4; j++) {
      float zi = fminf(fmaxf(z[0][j], -30.f), 30.f);  // NaN/overflow guard
      float zf = fminf(fmaxf(z[1][j], -30.f), 30.f);
      float zg = fminf(fmaxf(z[2][j], -30.f), 30.f);
      float zo = fminf(fmaxf(z[3][j], -30.f), 30.f);
      float iv = 1.0f / (1.0f + expf(-zi));
      float fv = 1.0f / (1.0f + expf(-zf));
      float gv = tanhf(zg);
      float ov = 1.0f / (1.0f + expf(-zo));
      float cn = fv * cstate[j] + iv * gv;
      cstate[j] = cn;
      up.s[j] = f2bf(ov * tanhf(cn));
    }
    __hip_atomic_store((u64_t*)(hO + (size_t)erow * 512 + col0), up.q, __ATOMIC_RELAXED,
                       __HIP_MEMORY_SCOPE_AGENT);
    if (l == 2 && T >= TT)
      *(u64_t*)(decouts + ((size_t)(T - TT) * 64 + erow) * 512 + col0) = up.q;

    // barrier drains all waves' vmcnt => h stores ack'd at LLC before publish
    __syncthreads();
    if (tid == 0)
      __hip_atomic_store(fgrp(flags, T, l) + cb * 32, 1, __ATOMIC_RELAXED,
                         __HIP_MEMORY_SCOPE_AGENT);
  }
}

extern "C" void kernel_launch(void* const* d_in, const int* in_sizes, int n_in, void* d_out,
                              int out_size, void* d_ws, size_t ws_size, hipStream_t stream) {
  const void* inputs = d_in[0];
  const void* targets = d_in[1];
  const void* input_embed = d_in[2];
  const void* enc_Wd = d_in[3];
  const void* enc_bd = d_in[4];
  const void* enc_Wx = d_in[5];
  const void* enc_Wh = d_in[6];
  const void* enc_b = d_in[7];
  const void* dec_embed = d_in[8];
  const void* dec_Wd = d_in[9];
  const void* dec_bd = d_in[10];
  const void* dec_Wx = d_in[11];
  const void* dec_Wh = d_in[12];
  const void* dec_b = d_in[13];
  const void* out_W1 = d_in[14];
  const void* out_b1 = d_in[15];
  const void* out_W2 = d_in[16];
  const void* out_b2 = d_in[17];

  char* ws = (char*)d_ws;
  size_t off = 0;
  auto alloc = [&](size_t bytes) {
    void* p = ws + off;
    off += (bytes + 255) & ~(size_t)255;
    return p;
  };
  int* mode = (int*)alloc(256);
  int* flags = (int*)alloc((size_t)768 * 1024 * 4);  // (T,l) x 32 slots x 128B
  ushort_t* encWd_t = (ushort_t*)alloc((size_t)512 * 64 * 2);
  ushort_t* encWx_t = (ushort_t*)alloc((size_t)3 * 2048 * 512 * 2);
  ushort_t* encWh_t = (ushort_t*)alloc((size_t)3 * 2048 * 512 * 2);
  ushort_t* decWd_t = (ushort_t*)alloc((size_t)512 * 2048 * 2);
  ushort_t* decWx_t = (ushort_t*)alloc((size_t)3 * 2048 * 512 * 2);
  ushort_t* decWh_t = (ushort_t*)alloc((size_t)3 * 2048 * 512 * 2);
  ushort_t* outW1_t = (ushort_t*)alloc((size_t)2048 * 512 * 2);
  ushort_t* encx = (ushort_t*)alloc((size_t)MROWS * EMBED * 2);
  ushort_t* encin = (ushort_t*)alloc((size_t)MROWS * 512 * 2);
  ushort_t* dect = (ushort_t*)alloc((size_t)MROWS * 2048 * 2);  // reused as out_W2^T
  ushort_t* decin = (ushort_t*)alloc((size_t)MROWS * 512 * 2);
  ushort_t* zbuf = (ushort_t*)alloc((size_t)MROWS * 2048 * 2);  // enc layer0 pre-acts
  ushort_t* hbuf = (ushort_t*)alloc((size_t)4 * 3 * 64 * 512 * 2);  // 4-deep ring
  ushort_t* decouts = (ushort_t*)alloc((size_t)MROWS * 512 * 2);
  ushort_t* h1 = (ushort_t*)alloc((size_t)MROWS * 2048 * 2);  // dec z1, then out1
  ushort_t* W2t = dect;

  hipMemsetAsync(hbuf, 0, (size_t)4 * 3 * 64 * 512 * 2, stream);
  hipMemsetAsync(flags, 0, (size_t)768 * 1024 * 4, stream);

  detect_mode<<<1, 256, 0, stream>>>(input_embed, targets, mode);

  gather_enc<<<256, 256, 0, stream>>>(mode, inputs, input_embed, encx);
  gather_dec<<<8192, 256, 0, stream>>>(mode, targets, dec_embed, dect);

  transpose_elems<<<dim3(16, 2), 256, 0, stream>>>(mode, enc_Wd, 0, encWd_t, 64, 512);
  for (int l = 0; l < 3; l++) {
    size_t eo = (size_t)l * 512 * 2048;  // element offset of layer l in [3,512,2048]
    size_t to = (size_t)l * 2048 * 512;
    transpose_elems<<<dim3(64, 16), 256, 0, stream>>>(mode, enc_Wx, eo, encWx_t + to, 512, 2048);
    transpose_elems<<<dim3(64, 16), 256, 0, stream>>>(mode, enc_Wh, eo, encWh_t + to, 512, 2048);
    transpose_elems<<<dim3(64, 16), 256, 0, stream>>>(mode, dec_Wx, eo, decWx_t + to, 512, 2048);
    transpose_elems<<<dim3(64, 16), 256, 0, stream>>>(mode, dec_Wh, eo, decWh_t + to, 512, 2048);
  }
  transpose_elems<<<dim3(16, 64), 256, 0, stream>>>(mode, dec_Wd, 0, decWd_t, 2048, 512);
  transpose_elems<<<dim3(64, 16), 256, 0, stream>>>(mode, out_W1, 0, outW1_t, 512, 2048);

  // enc dense -> encin; enc layer0 pre-acts -> zbuf
  gemm_bt<1, 1, 0><<<dim3(4, 64), 256, 0, stream>>>(mode, encx, encWd_t, enc_bd, encin, MROWS, 512, 64);
  gemm_bt<0, 0, 0><<<dim3(16, 64), 256, 0, stream>>>(mode, encin, encWx_t, nullptr, zbuf, MROWS, 2048, 512);
  // dec dense -> decin; dec layer0 pre-acts -> h1 (independent of encoder)
  gemm_bt<1, 1, 0><<<dim3(4, 64), 256, 0, stream>>>(mode, dect, decWd_t, dec_bd, decin, MROWS, 512, 2048);
  gemm_bt<0, 0, 0><<<dim3(16, 64), 256, 0, stream>>>(mode, decin, decWx_t, nullptr, h1, MROWS, 2048, 512);
  transpose_elems<<<dim3(256, 64), 256, 0, stream>>>(mode, out_W2, 0, W2t, 2048, 8192);

  // Merged enc+dec recurrence: one persistent pipelined kernel (T = 0..255)
  lstm_persist<<<96, 256, 0, stream>>>(mode, zbuf, h1, encWx_t, encWh_t, enc_b, decWx_t, decWh_t,
                                       dec_b, hbuf, decouts, flags);

  gemm_bt<1, 1, 0><<<dim3(16, 64), 256, 0, stream>>>(mode, decouts, outW1_t, out_b1, h1, MROWS, 2048, 512);
  gemm_bt<1, 1, 1><<<dim3(64, 64), 256, 0, stream>>>(mode, h1, W2t, out_b2, d_out, MROWS, PATHN, 2048);
}